// Round 2
// baseline (401.899 us; speedup 1.0000x reference)
//
#include <hip/hip_runtime.h>

// Problem sizes (fixed)
#define S_IN 256
#define IN_PB (S_IN * S_IN * S_IN)     // 16,777,216 per batch
#define D1_PB (128 * 128 * 128)        // 2,097,152
#define D2_PB (64 * 64 * 64)           // 262,144
#define X_ELEMS (2 * IN_PB)
#define D1_ELEMS (2 * D1_PB)

// Tile config: 16^3 input tile per block, halo 2 each side for the 5x5x5 kernel
#define T 16
#define L 20                 // T + 4
#define LROW 21              // padded x-stride (break 32-bank structure)
#define LSLAB (L * LROW)     // 420 floats per z-slice
#define LDS_TOT (L * LSLAB)  // 8400 floats = 33.6 KB

__global__ __launch_bounds__(256, 4) void pyramid_fused_kernel(
    const float* __restrict__ x, const float* __restrict__ k0,
    const float* __restrict__ k1, float* __restrict__ out0,
    float* __restrict__ out1, float* __restrict__ out2)
{
    __shared__ float tile[LDS_TOT];
    __shared__ float kw1[27];
    __shared__ float kw2[125];

    const int tid = threadIdx.x;
    const int bx = blockIdx.x;          // x tile  (0..15)
    const int by = blockIdx.y;          // y tile  (0..15)
    const int bz = blockIdx.z & 15;     // z tile  (0..15)
    const int n  = blockIdx.z >> 4;     // batch   (0..1)

    if (tid < 27) kw1[tid] = k0[tid];
    if (tid >= 32 && tid < 157) kw2[tid - 32] = k1[tid - 32];

    const float* xb = x + (size_t)n * IN_PB;
    const int tx0 = bx * T - 2, ty0 = by * T - 2, tz0 = bz * T - 2;

    // ---- Stage input tile + halo into LDS, edge-replicate clamp at load ----
    for (int i = tid; i < L * L * L; i += 256) {
        int lx = i % L;
        int t2 = i / L;
        int ly = t2 % L;
        int lz = t2 / L;
        int gx = min(max(tx0 + lx, 0), S_IN - 1);
        int gy = min(max(ty0 + ly, 0), S_IN - 1);
        int gz = min(max(tz0 + lz, 0), S_IN - 1);
        tile[lz * LSLAB + ly * LROW + lx] =
            xb[((((size_t)gz << 8) + gy) << 8) + gx];
    }
    __syncthreads();

    // ---- 1) Passthrough copy of the 16^3 interior ----
    {
        const size_t ob0 = (size_t)n * IN_PB;
        for (int i = tid; i < T * T * T; i += 256) {
            int lx = i & 15, ly = (i >> 4) & 15, lz = i >> 8;
            float v = tile[(lz + 2) * LSLAB + (ly + 2) * LROW + (lx + 2)];
            size_t gz = (size_t)(bz * T + lz);
            out0[ob0 + (((gz << 8) + (by * T + ly)) << 8) + (bx * T + lx)] = v;
        }
    }

    // ---- 2) d1: 3x3x3 blur, stride 2 -> 8^3 outputs per tile ----
    for (int i = tid; i < 8 * 8 * 8; i += 256) {
        int w = i & 7, h = (i >> 3) & 7, d = i >> 6;
        float acc = 0.0f;
#pragma unroll
        for (int a = 0; a < 3; ++a) {
#pragma unroll
            for (int b = 0; b < 3; ++b) {
                const float* r =
                    &tile[(2 * d + 1 + a) * LSLAB + (2 * h + 1 + b) * LROW + (2 * w + 1)];
                const float* kr = &kw1[(a * 3 + b) * 3];
                acc = fmaf(kr[0], r[0], acc);
                acc = fmaf(kr[1], r[1], acc);
                acc = fmaf(kr[2], r[2], acc);
            }
        }
        out1[(size_t)n * D1_PB +
             (((size_t)(bz * 8 + d) << 7) + (by * 8 + h) << 7) + (bx * 8 + w)] = acc;
    }

    // ---- 3) d2: 5x5x5 blur, stride 4 -> 4^3 outputs per tile ----
    if (tid < 64) {
        int w = tid & 3, h = (tid >> 2) & 3, d = tid >> 4;
        float acc = 0.0f;
#pragma unroll
        for (int a = 0; a < 5; ++a) {
#pragma unroll
            for (int b = 0; b < 5; ++b) {
                const float* r =
                    &tile[(4 * d + a) * LSLAB + (4 * h + b) * LROW + (4 * w)];
                const float* kr = &kw2[(a * 5 + b) * 5];
                acc = fmaf(kr[0], r[0], acc);
                acc = fmaf(kr[1], r[1], acc);
                acc = fmaf(kr[2], r[2], acc);
                acc = fmaf(kr[3], r[3], acc);
                acc = fmaf(kr[4], r[4], acc);
            }
        }
        out2[(size_t)n * D2_PB +
             (((size_t)(bz * 4 + d) << 6) + (by * 4 + h) << 6) + (bx * 4 + w)] = acc;
    }
}

extern "C" void kernel_launch(void* const* d_in, const int* in_sizes, int n_in,
                              void* d_out, int out_size, void* d_ws, size_t ws_size,
                              hipStream_t stream) {
    const float* x  = (const float*)d_in[0];
    const float* k0 = (const float*)d_in[1];   // 27 floats (3x3x3)
    const float* k1 = (const float*)d_in[2];   // 125 floats (5x5x5)

    float* out0 = (float*)d_out;               // x passthrough
    float* out1 = out0 + X_ELEMS;              // d1
    float* out2 = out1 + D1_ELEMS;             // d2

    dim3 grid(16, 16, 32);                     // 16x16x(16 z-tiles x 2 batches)
    pyramid_fused_kernel<<<grid, 256, 0, stream>>>(x, k0, k1, out0, out1, out2);
}

// Round 3
// 391.427 us; speedup vs baseline: 1.0268x; 1.0268x over previous
//
#include <hip/hip_runtime.h>

// Problem sizes (fixed)
#define S_IN 256
#define IN_PB (S_IN * S_IN * S_IN)     // 16,777,216 per batch
#define D1_PB (128 * 128 * 128)        // 2,097,152
#define D2_PB (64 * 64 * 64)           // 262,144
#define X_ELEMS (2 * IN_PB)
#define D1_ELEMS (2 * D1_PB)

// Tile: interior 64(x) x 8(y) x 8(z); halo 2 each side
#define TX 64
#define TY 8
#define TZ 8
#define LX 68
#define LY 12
#define LZ 12
#define LSLAB (LX * LY)            // 816 floats per z-slice
#define LDS_TOT (LX * LY * LZ)     // 9792 floats = 39168 B

__global__ __launch_bounds__(256, 4) void pyramid_fused_kernel(
    const float* __restrict__ x, const float* __restrict__ k0,
    const float* __restrict__ k1, float* __restrict__ out0,
    float* __restrict__ out1, float* __restrict__ out2)
{
    __shared__ float tile[LDS_TOT];
    __shared__ float kw1[27];
    __shared__ float kw2[125];

    const int tid = threadIdx.x;
    const int bx = blockIdx.x;          // x tile (0..3)
    const int by = blockIdx.y;          // y tile (0..31)
    const int bz = blockIdx.z & 31;     // z tile (0..31)
    const int n  = blockIdx.z >> 5;     // batch  (0..1)

    if (tid < 27) kw1[tid] = k0[tid];
    if (tid >= 32 && tid < 157) kw2[tid - 32] = k1[tid - 32];

    const float* xb = x + (size_t)n * IN_PB;
    const int tx0 = bx * TX - 2, ty0 = by * TY - 2, tz0 = bz * TZ - 2;

    // ---- Stage 68x12x12 tile (edge-replicate clamp). Rows are 68 contiguous
    // floats -> coalesced loads, conflict-free LDS writes.
    for (int i = tid; i < LDS_TOT; i += 256) {
        int lx = i % LX;
        int r  = i / LX;
        int ly = r % LY;
        int lz = r / LY;
        int gx = min(max(tx0 + lx, 0), S_IN - 1);
        int gy = min(max(ty0 + ly, 0), S_IN - 1);
        int gz = min(max(tz0 + lz, 0), S_IN - 1);
        tile[lz * LSLAB + ly * LX + lx] =
            xb[((((size_t)gz << 8) + gy) << 8) + gx];
    }
    __syncthreads();

    // ---- 1) Passthrough: 64-wide rows -> 256B per wave, fully coalesced ----
    {
        const size_t ob0 = (size_t)n * IN_PB;
        for (int i = tid; i < TX * TY * TZ; i += 256) {
            int lx = i & 63, ly = (i >> 6) & 7, lz = i >> 9;
            float v = tile[(lz + 2) * LSLAB + (ly + 2) * LX + (lx + 2)];
            out0[ob0 + ((((size_t)(bz * TZ + lz) << 8) + (by * TY + ly)) << 8)
                     + (bx * TX + lx)] = v;
        }
    }

    // ---- 2) d1: 3x3x3 stride 2 -> 32x4x4 outputs per tile ----
    for (int i = tid; i < 32 * 4 * 4; i += 256) {
        int w = i & 31, h = (i >> 5) & 3, d = i >> 7;
        float acc = 0.0f;
#pragma unroll
        for (int a = 0; a < 3; ++a) {
#pragma unroll
            for (int b = 0; b < 3; ++b) {
                const float* r =
                    &tile[(2 * d + 1 + a) * LSLAB + (2 * h + 1 + b) * LX + (2 * w + 1)];
                const float* kr = &kw1[(a * 3 + b) * 3];
                acc = fmaf(kr[0], r[0], acc);
                acc = fmaf(kr[1], r[1], acc);
                acc = fmaf(kr[2], r[2], acc);
            }
        }
        out1[(size_t)n * D1_PB +
             (((size_t)(bz * 4 + d) * 128 + (by * 4 + h)) * 128) + (bx * 32 + w)] = acc;
    }

    // ---- 3) d2: 5x5x5 stride 4 -> 16x2x2 outputs per tile ----
    if (tid < 64) {
        int w = tid & 15, h = (tid >> 4) & 1, d = tid >> 5;
        float acc = 0.0f;
#pragma unroll
        for (int a = 0; a < 5; ++a) {
#pragma unroll
            for (int b = 0; b < 5; ++b) {
                const float* r =
                    &tile[(4 * d + a) * LSLAB + (4 * h + b) * LX + (4 * w)];
                const float* kr = &kw2[(a * 5 + b) * 5];
                acc = fmaf(kr[0], r[0], acc);
                acc = fmaf(kr[1], r[1], acc);
                acc = fmaf(kr[2], r[2], acc);
                acc = fmaf(kr[3], r[3], acc);
                acc = fmaf(kr[4], r[4], acc);
            }
        }
        out2[(size_t)n * D2_PB +
             (((size_t)(bz * 2 + d) * 64 + (by * 2 + h)) * 64) + (bx * 16 + w)] = acc;
    }
}

extern "C" void kernel_launch(void* const* d_in, const int* in_sizes, int n_in,
                              void* d_out, int out_size, void* d_ws, size_t ws_size,
                              hipStream_t stream) {
    const float* x  = (const float*)d_in[0];
    const float* k0 = (const float*)d_in[1];   // 27 floats (3x3x3)
    const float* k1 = (const float*)d_in[2];   // 125 floats (5x5x5)

    float* out0 = (float*)d_out;               // x passthrough
    float* out1 = out0 + X_ELEMS;              // d1
    float* out2 = out1 + D1_ELEMS;             // d2

    dim3 grid(4, 32, 64);                      // 4 x-tiles, 32 y, 32 z x 2 batches
    pyramid_fused_kernel<<<grid, 256, 0, stream>>>(x, k0, k1, out0, out1, out2);
}